// Round 1
// baseline (3147.866 us; speedup 1.0000x reference)
//
#include <hip/hip_runtime.h>
#include <hip/hip_bf16.h>
#include <math.h>

#define B_TOTAL 131072
#define NX 64
#define H 512
#define LD 8
#define NT 45          // 1 + 8 + 36
#define NSTEPS 20
#define R 16           // rows per block
#define STRIDE 520     // H + 8 pad; 520*4 B = 2080 = 130*16 -> float4-aligned rows
#define NTHREADS 256

__device__ __forceinline__ float silu_f(float v) {
    return v / (1.0f + __expf(-v));
}

// In-place LayerNorm (+gamma,beta) + SiLU over rows of width H in buf.
// 16 lanes per row, lanes of one row always within one wave -> shfl reduce.
__device__ __forceinline__ void ln_silu(float buf[R][STRIDE],
                                        const float* __restrict__ g,
                                        const float* __restrict__ be, int t) {
    const int r = t >> 4;
    const int lane = t & 15;
    float s1 = 0.f, s2 = 0.f;
#pragma unroll
    for (int j = 0; j < H / 16; ++j) {
        float v = buf[r][lane + 16 * j];
        s1 += v;
        s2 += v * v;
    }
#pragma unroll
    for (int m = 8; m >= 1; m >>= 1) {
        s1 += __shfl_xor(s1, m, 16);
        s2 += __shfl_xor(s2, m, 16);
    }
    const float mean = s1 * (1.0f / H);
    const float var  = s2 * (1.0f / H) - mean * mean;
    const float rstd = rsqrtf(var + 1e-5f);
#pragma unroll
    for (int j = 0; j < H / 16; ++j) {
        const int c = lane + 16 * j;
        float v = buf[r][c];
        float h = (v - mean) * rstd * g[c] + be[c];
        buf[r][c] = silu_f(h);
    }
}

// GEMM: out[r][c] = sum_k in[r][k] * W[k*H + c] + b[c], c in [0,512), K template.
// Thread t owns columns {t, t+256} for all R rows.
template <int K>
__device__ __forceinline__ void gemmK(const float in[R][STRIDE], float out[R][STRIDE],
                                      const float* __restrict__ W,
                                      const float* __restrict__ b, int t) {
    const int c0 = t, c1 = t + 256;
    float acc0[R], acc1[R];
#pragma unroll
    for (int r = 0; r < R; ++r) { acc0[r] = 0.f; acc1[r] = 0.f; }

    for (int k = 0; k < K; k += 4) {
        const float w00 = W[(k + 0) * H + c0], w10 = W[(k + 0) * H + c1];
        const float w01 = W[(k + 1) * H + c0], w11 = W[(k + 1) * H + c1];
        const float w02 = W[(k + 2) * H + c0], w12 = W[(k + 2) * H + c1];
        const float w03 = W[(k + 3) * H + c0], w13 = W[(k + 3) * H + c1];
#pragma unroll
        for (int r = 0; r < R; ++r) {
            const float4 h = *(const float4*)&in[r][k];   // broadcast ds_read_b128
            acc0[r] += h.x * w00 + h.y * w01 + h.z * w02 + h.w * w03;
            acc1[r] += h.x * w10 + h.y * w11 + h.z * w12 + h.w * w13;
        }
    }
    const float b0 = b[c0], b1 = b[c1];
#pragma unroll
    for (int r = 0; r < R; ++r) {
        out[r][c0] = acc0[r] + b0;
        out[r][c1] = acc1[r] + b1;
    }
}

__global__ __launch_bounds__(NTHREADS, 2) void sindy_fused_kernel(
    const float* __restrict__ x0, const float* __restrict__ logdt,
    const float* __restrict__ eW1, const float* __restrict__ eb1,
    const float* __restrict__ eg1, const float* __restrict__ ebe1,
    const float* __restrict__ eW2, const float* __restrict__ eb2,
    const float* __restrict__ eg2, const float* __restrict__ ebe2,
    const float* __restrict__ eW3, const float* __restrict__ eb3,
    const float* __restrict__ dW1, const float* __restrict__ db1,
    const float* __restrict__ dg1, const float* __restrict__ dbe1,
    const float* __restrict__ dW2, const float* __restrict__ db2,
    const float* __restrict__ dg2, const float* __restrict__ dbe2,
    const float* __restrict__ dW3, const float* __restrict__ db3,
    const float* __restrict__ Xi, float* __restrict__ out) {
    __shared__ float sA[R][STRIDE];
    __shared__ float sB[R][STRIDE];
    __shared__ float zbuf[R][LD];
    __shared__ float dtb[R];
    __shared__ float xis[NT * LD];

    const int t = threadIdx.x;
    const int row0 = blockIdx.x * R;

    // Stage Xi, per-row dt, and the x tile.
    for (int i = t; i < NT * LD; i += NTHREADS) xis[i] = Xi[i];
    if (t < R) dtb[t] = logdt[row0 + t] * (1.0f / NSTEPS);
    {
        const int r = t >> 4, k4 = (t & 15) * 4;    // 16 rows x 64 cols as float4
        const float4 v = *(const float4*)&x0[(row0 + r) * NX + k4];
        *(float4*)&sB[r][k4] = v;
    }
    __syncthreads();

    // ---- encoder layer 1: x(64) -> 512, LN, SiLU ----
    gemmK<NX>(sB, sA, eW1, eb1, t);
    __syncthreads();
    ln_silu(sA, eg1, ebe1, t);
    __syncthreads();

    // ---- encoder layer 2: 512 -> 512, LN, SiLU ----
    gemmK<H>(sA, sB, eW2, eb2, t);
    __syncthreads();
    ln_silu(sB, eg2, ebe2, t);
    __syncthreads();

    // ---- encoder layer 3: 512 -> 8, tanh -> z0 ----
    if (t < R * LD) {
        const int r = t >> 3, c = t & 7;
        float acc = 0.f;
        for (int k = 0; k < H; k += 4) {
            const float4 h = *(const float4*)&sB[r][k];
            acc += h.x * eW3[(k + 0) * LD + c] + h.y * eW3[(k + 1) * LD + c] +
                   h.z * eW3[(k + 2) * LD + c] + h.w * eW3[(k + 3) * LD + c];
        }
        zbuf[r][c] = tanhf(acc + eb3[c]);
    }
    __syncthreads();

    // ---- SINDy Euler integration: 20 steps of z += (Theta(z) @ Xi) * dt ----
    for (int s = 0; s < NSTEPS; ++s) {
        float zn = 0.f;
        const int r = t >> 3, c = t & 7;
        if (t < R * LD) {
            float z[LD];
#pragma unroll
            for (int j = 0; j < LD; ++j) z[j] = zbuf[r][j];
            float zd = xis[c];                       // constant term
#pragma unroll
            for (int j = 0; j < LD; ++j) zd += z[j] * xis[(1 + j) * LD + c];
            int idx = 1 + LD;
#pragma unroll
            for (int i = 0; i < LD; ++i) {
#pragma unroll
                for (int j = i; j < LD; ++j) {
                    zd += z[i] * z[j] * xis[idx * LD + c];
                    ++idx;
                }
            }
            zn = z[c] + zd * dtb[r];
        }
        __syncthreads();
        if (t < R * LD) zbuf[r][c] = zn;
        __syncthreads();
    }

    // ---- decoder layer 1: 8 -> 512, LN, SiLU ----
    {
        const int c0 = t, c1 = t + 256;
        float acc0[R], acc1[R];
#pragma unroll
        for (int r = 0; r < R; ++r) { acc0[r] = 0.f; acc1[r] = 0.f; }
#pragma unroll
        for (int k = 0; k < LD; ++k) {
            const float w0 = dW1[k * H + c0], w1 = dW1[k * H + c1];
#pragma unroll
            for (int r = 0; r < R; ++r) {
                const float zv = zbuf[r][k];
                acc0[r] += zv * w0;
                acc1[r] += zv * w1;
            }
        }
        const float b0 = db1[c0], b1v = db1[c1];
#pragma unroll
        for (int r = 0; r < R; ++r) {
            sA[r][c0] = acc0[r] + b0;
            sA[r][c1] = acc1[r] + b1v;
        }
    }
    __syncthreads();
    ln_silu(sA, dg1, dbe1, t);
    __syncthreads();

    // ---- decoder layer 2: 512 -> 512, LN, SiLU ----
    gemmK<H>(sA, sB, dW2, db2, t);
    __syncthreads();
    ln_silu(sB, dg2, dbe2, t);
    __syncthreads();

    // ---- decoder layer 3: 512 -> 64, + bias, store ----
    {
        const int c = t & 63;
        const int rb = t >> 6;                        // 0..3
        float acc[4] = {0.f, 0.f, 0.f, 0.f};
        for (int k = 0; k < H; k += 4) {
            const float w0 = dW3[(k + 0) * NX + c];
            const float w1 = dW3[(k + 1) * NX + c];
            const float w2 = dW3[(k + 2) * NX + c];
            const float w3 = dW3[(k + 3) * NX + c];
#pragma unroll
            for (int i = 0; i < 4; ++i) {
                const int r = rb + 4 * i;
                const float4 h = *(const float4*)&sB[r][k];
                acc[i] += h.x * w0 + h.y * w1 + h.z * w2 + h.w * w3;
            }
        }
        const float bb = db3[c];
#pragma unroll
        for (int i = 0; i < 4; ++i) {
            const int r = rb + 4 * i;
            out[(row0 + r) * NX + c] = acc[i] + bb;
        }
    }
}

extern "C" void kernel_launch(void* const* d_in, const int* in_sizes, int n_in,
                              void* d_out, int out_size, void* d_ws, size_t ws_size,
                              hipStream_t stream) {
    const float* x0    = (const float*)d_in[0];
    const float* logdt = (const float*)d_in[1];
    // d_in[2], d_in[3]: Dt_mean / Dt_std — unused by the reference.
    const float* eW1  = (const float*)d_in[4];
    const float* eb1  = (const float*)d_in[5];
    const float* eg1  = (const float*)d_in[6];
    const float* ebe1 = (const float*)d_in[7];
    const float* eW2  = (const float*)d_in[8];
    const float* eb2  = (const float*)d_in[9];
    const float* eg2  = (const float*)d_in[10];
    const float* ebe2 = (const float*)d_in[11];
    const float* eW3  = (const float*)d_in[12];
    const float* eb3  = (const float*)d_in[13];
    const float* dW1  = (const float*)d_in[14];
    const float* db1  = (const float*)d_in[15];
    const float* dg1  = (const float*)d_in[16];
    const float* dbe1 = (const float*)d_in[17];
    const float* dW2  = (const float*)d_in[18];
    const float* db2  = (const float*)d_in[19];
    const float* dg2  = (const float*)d_in[20];
    const float* dbe2 = (const float*)d_in[21];
    const float* dW3  = (const float*)d_in[22];
    const float* db3  = (const float*)d_in[23];
    const float* Xi   = (const float*)d_in[24];
    float* out = (float*)d_out;

    dim3 grid(B_TOTAL / R);
    dim3 block(NTHREADS);
    sindy_fused_kernel<<<grid, block, 0, stream>>>(
        x0, logdt, eW1, eb1, eg1, ebe1, eW2, eb2, eg2, ebe2, eW3, eb3,
        dW1, db1, dg1, dbe1, dW2, db2, dg2, dbe2, dW3, db3, Xi, out);
}

// Round 2
// 863.650 us; speedup vs baseline: 3.6448x; 3.6448x over previous
//
#include <hip/hip_runtime.h>
#include <hip/hip_bf16.h>
#include <math.h>

#define B_TOTAL 131072
#define NX 64
#define H 512
#define LD 8
#define NT 45          // 1 + 8 + 36
#define NSTEPS 20

// ---- main MFMA kernel config ----
#define ROWS 32        // rows per block
#define NTH 512        // 8 waves
#define ASTR 520       // bf16 elements per activation row (520*2B=1040B: 2-way bank alias only)

// ws layout (bf16 elements): W^T [n][k]
#define OFF_EW1T 0                    // [512][64]
#define OFF_EW2T 32768                // [512][512]
#define OFF_DW2T 294912               // [512][512]
#define OFF_DW3T 557056               // [64][512]
#define WS_ELEMS 589824               // * 2 bytes = 1,179,648

typedef __attribute__((ext_vector_type(8))) short short8;
typedef __attribute__((ext_vector_type(4))) short short4v;
typedef __attribute__((ext_vector_type(4))) float f32x4;

__device__ __forceinline__ ushort f2bf(float f) {
    union { float f; uint u; } v; v.f = f;
    uint u = v.u;
    u += 0x7fff + ((u >> 16) & 1);          // RNE
    return (ushort)(u >> 16);
}
__device__ __forceinline__ float bf2f(ushort s) {
    union { uint u; float f; } v; v.u = ((uint)s) << 16;
    return v.f;
}
__device__ __forceinline__ float silu_f(float v) {
    return v / (1.0f + __expf(-v));
}

// ---------------- weight prep: fp32 row-major [k][n] -> bf16 W^T [n][k] ----------------
__global__ void prep_weights(const float* __restrict__ eW1, const float* __restrict__ eW2,
                             const float* __restrict__ dW2, const float* __restrict__ dW3,
                             short* __restrict__ ws) {
    const int id = blockIdx.x * 256 + threadIdx.x;
    if (id < OFF_EW2T) {                               // eW1T[n][k], n<512, k<64
        const int n = id >> 6, k = id & 63;
        ws[id] = (short)f2bf(eW1[k * H + n]);
    } else if (id < OFF_DW2T) {                        // eW2T[n][k], 512x512
        const int j = id - OFF_EW2T, n = j >> 9, k = j & 511;
        ws[id] = (short)f2bf(eW2[k * H + n]);
    } else if (id < OFF_DW3T) {                        // dW2T
        const int j = id - OFF_DW2T, n = j >> 9, k = j & 511;
        ws[id] = (short)f2bf(dW2[k * H + n]);
    } else if (id < WS_ELEMS) {                        // dW3T[n][k], n<64, k<512
        const int j = id - OFF_DW3T, n = j >> 9, k = j & 511;
        ws[id] = (short)f2bf(dW3[k * NX + n]);
    }
}

// ---------------- big GEMM: act[32][K] (bf16 LDS) @ W(KxN=512) via W^T bf16 global ----------------
// Wave w owns cols [w*64, w*64+64), both 16-row m-tiles. acc[mt][tile] = 16x16 MFMA C frag.
template <int K>
__device__ __forceinline__ void gemm_mfma(const short (*act)[ASTR], const short* __restrict__ WT,
                                          f32x4 acc[2][4], int w, int lane) {
    const int lm = lane & 15, q = lane >> 4;
#pragma unroll 2
    for (int kc = 0; kc < K / 32; ++kc) {
        const int k0 = kc * 32 + q * 8;
        short8 a0 = *(const short8*)&act[lm][k0];
        short8 a1 = *(const short8*)&act[16 + lm][k0];
#pragma unroll
        for (int t = 0; t < 4; ++t) {
            short8 b = *(const short8*)&WT[(w * 64 + t * 16 + lm) * K + k0];
            acc[0][t] = __builtin_amdgcn_mfma_f32_16x16x32_bf16(a0, b, acc[0][t], 0, 0, 0);
            acc[1][t] = __builtin_amdgcn_mfma_f32_16x16x32_bf16(a1, b, acc[1][t], 0, 0, 0);
        }
    }
}

// bias + LayerNorm + SiLU on MFMA C-layout accumulators, store bf16 to dst.
// C-layout: value (row = mt*16 + q*4 + reg, col = w*64 + t*16 + lm).
__device__ __forceinline__ void ln_silu_store(f32x4 acc[2][4],
        const float* __restrict__ bias, const float* __restrict__ g, const float* __restrict__ be,
        short (*dst)[ASTR], float (*p1)[8], float (*p2)[8], float (*rstat)[2],
        int w, int lane, int tid) {
    const int lm = lane & 15, q = lane >> 4;
    float cb[4], cg[4], cbe[4];
#pragma unroll
    for (int t = 0; t < 4; ++t) {
        const int c = w * 64 + t * 16 + lm;
        cb[t] = bias[c]; cg[t] = g[c]; cbe[t] = be[c];
    }
    float s1[8], s2[8];
#pragma unroll
    for (int i = 0; i < 8; ++i) { s1[i] = 0.f; s2[i] = 0.f; }
#pragma unroll
    for (int mt = 0; mt < 2; ++mt)
#pragma unroll
        for (int t = 0; t < 4; ++t)
#pragma unroll
            for (int r = 0; r < 4; ++r) {
                float v = acc[mt][t][r] + cb[t];
                acc[mt][t][r] = v;
                s1[mt * 4 + r] += v;
                s2[mt * 4 + r] += v * v;
            }
#pragma unroll
    for (int m = 1; m < 16; m <<= 1) {
#pragma unroll
        for (int i = 0; i < 8; ++i) {
            s1[i] += __shfl_xor(s1[i], m);
            s2[i] += __shfl_xor(s2[i], m);
        }
    }
    if (lm == 0) {
#pragma unroll
        for (int i = 0; i < 8; ++i) {
            const int row = (i >> 2) * 16 + q * 4 + (i & 3);
            p1[row][w] = s1[i];
            p2[row][w] = s2[i];
        }
    }
    __syncthreads();
    if (tid < ROWS) {
        float a = 0.f, b2 = 0.f;
#pragma unroll
        for (int j = 0; j < 8; ++j) { a += p1[tid][j]; b2 += p2[tid][j]; }
        const float mean = a * (1.0f / H);
        rstat[tid][0] = mean;
        rstat[tid][1] = rsqrtf(b2 * (1.0f / H) - mean * mean + 1e-5f);
    }
    __syncthreads();
#pragma unroll
    for (int mt = 0; mt < 2; ++mt) {
#pragma unroll
        for (int r = 0; r < 4; ++r) {
            const int row = mt * 16 + q * 4 + r;
            const float mu = rstat[row][0], rs = rstat[row][1];
#pragma unroll
            for (int t = 0; t < 4; ++t) {
                const float v = (acc[mt][t][r] - mu) * rs * cg[t] + cbe[t];
                dst[row][w * 64 + t * 16 + lm] = (short)f2bf(silu_f(v));
            }
        }
    }
    __syncthreads();
}

__global__ __launch_bounds__(NTH, 4) void sindy_mfma_kernel(
    const float* __restrict__ x0, const float* __restrict__ logdt,
    const float* __restrict__ eb1, const float* __restrict__ eg1, const float* __restrict__ ebe1,
    const float* __restrict__ eb2, const float* __restrict__ eg2, const float* __restrict__ ebe2,
    const float* __restrict__ eW3, const float* __restrict__ eb3,
    const float* __restrict__ dW1, const float* __restrict__ db1,
    const float* __restrict__ dg1, const float* __restrict__ dbe1,
    const float* __restrict__ db2, const float* __restrict__ dg2, const float* __restrict__ dbe2,
    const float* __restrict__ db3, const float* __restrict__ Xi,
    const short* __restrict__ wsb, float* __restrict__ out) {
    __shared__ __align__(16) short actA[ROWS][ASTR];
    __shared__ __align__(16) short actB[ROWS][ASTR];
    __shared__ float part1[ROWS][8], part2[ROWS][8];
    __shared__ float rowstat[ROWS][2];
    __shared__ float zbuf[ROWS][LD];
    __shared__ float dtb[ROWS];
    __shared__ float xis[NT * LD];

    const int tid = threadIdx.x;
    const int w = tid >> 6, lane = tid & 63;
    const int lm = lane & 15, q = lane >> 4;
    const int row0 = blockIdx.x * ROWS;

    const short* eW1T = wsb + OFF_EW1T;
    const short* eW2T = wsb + OFF_EW2T;
    const short* dW2T = wsb + OFF_DW2T;
    const short* dW3T = wsb + OFF_DW3T;

    // ---- stage Xi, dt, x (fp32 -> bf16 LDS) ----
    for (int i = tid; i < NT * LD; i += NTH) xis[i] = Xi[i];
    if (tid < ROWS) dtb[tid] = logdt[row0 + tid] * (1.0f / NSTEPS);
    {
        const int r = tid >> 4, c4 = (tid & 15) * 4;
        const float4 v = *(const float4*)&x0[(row0 + r) * NX + c4];
        short4v sv;
        sv[0] = (short)f2bf(v.x); sv[1] = (short)f2bf(v.y);
        sv[2] = (short)f2bf(v.z); sv[3] = (short)f2bf(v.w);
        *(short4v*)&actA[r][c4] = sv;
    }
    __syncthreads();

    // ---- encoder layer 1: 64 -> 512 (MFMA), LN+SiLU -> actB ----
    {
        f32x4 acc[2][4];
#pragma unroll
        for (int mt = 0; mt < 2; ++mt)
#pragma unroll
            for (int t = 0; t < 4; ++t) acc[mt][t] = (f32x4){0.f, 0.f, 0.f, 0.f};
        gemm_mfma<NX>(actA, eW1T, acc, w, lane);
        ln_silu_store(acc, eb1, eg1, ebe1, actB, part1, part2, rowstat, w, lane, tid);
    }

    // ---- encoder layer 2: 512 -> 512 (MFMA), LN+SiLU -> actA ----
    {
        f32x4 acc[2][4];
#pragma unroll
        for (int mt = 0; mt < 2; ++mt)
#pragma unroll
            for (int t = 0; t < 4; ++t) acc[mt][t] = (f32x4){0.f, 0.f, 0.f, 0.f};
        gemm_mfma<H>(actB, eW2T, acc, w, lane);
        ln_silu_store(acc, eb2, eg2, ebe2, actA, part1, part2, rowstat, w, lane, tid);
    }

    // ---- encoder layer 3: 512 -> 8, tanh -> z0 (fp32) ----
    if (tid < ROWS * LD) {
        const int r = tid >> 3, c = tid & 7;
        float s = 0.f;
        for (int k = 0; k < H; k += 8) {
            short8 hv = *(const short8*)&actA[r][k];
#pragma unroll
            for (int j = 0; j < 8; ++j)
                s += bf2f((ushort)hv[j]) * eW3[(k + j) * LD + c];
        }
        zbuf[r][c] = tanhf(s + eb3[c]);
    }
    __syncthreads();

    // ---- SINDy Euler integration (fp32) ----
    for (int st = 0; st < NSTEPS; ++st) {
        float zn = 0.f;
        const int r = tid >> 3, c = tid & 7;
        if (tid < ROWS * LD) {
            float z[LD];
#pragma unroll
            for (int j = 0; j < LD; ++j) z[j] = zbuf[r][j];
            float zd = xis[c];
#pragma unroll
            for (int j = 0; j < LD; ++j) zd += z[j] * xis[(1 + j) * LD + c];
            int idx = 1 + LD;
#pragma unroll
            for (int i = 0; i < LD; ++i)
#pragma unroll
                for (int j = i; j < LD; ++j) {
                    zd += z[i] * z[j] * xis[idx * LD + c];
                    ++idx;
                }
            zn = z[c] + zd * dtb[r];
        }
        __syncthreads();
        if (tid < ROWS * LD) zbuf[r][c] = zn;
        __syncthreads();
    }

    // ---- decoder layer 1: 8 -> 512 (fp32, MFMA-C-layout), LN+SiLU -> actB ----
    {
        float wc[4][LD];
#pragma unroll
        for (int t = 0; t < 4; ++t) {
            const int c = w * 64 + t * 16 + lm;
#pragma unroll
            for (int k = 0; k < LD; ++k) wc[t][k] = dW1[k * H + c];
        }
        f32x4 acc[2][4];
#pragma unroll
        for (int mt = 0; mt < 2; ++mt)
#pragma unroll
            for (int r = 0; r < 4; ++r) {
                const int row = mt * 16 + q * 4 + r;
                float z[LD];
#pragma unroll
                for (int k = 0; k < LD; ++k) z[k] = zbuf[row][k];
#pragma unroll
                for (int t = 0; t < 4; ++t) {
                    float s = 0.f;
#pragma unroll
                    for (int k = 0; k < LD; ++k) s += z[k] * wc[t][k];
                    acc[mt][t][r] = s;
                }
            }
        ln_silu_store(acc, db1, dg1, dbe1, actB, part1, part2, rowstat, w, lane, tid);
    }

    // ---- decoder layer 2: 512 -> 512 (MFMA), LN+SiLU -> actA ----
    {
        f32x4 acc[2][4];
#pragma unroll
        for (int mt = 0; mt < 2; ++mt)
#pragma unroll
            for (int t = 0; t < 4; ++t) acc[mt][t] = (f32x4){0.f, 0.f, 0.f, 0.f};
        gemm_mfma<H>(actB, dW2T, acc, w, lane);
        ln_silu_store(acc, db2, dg2, dbe2, actA, part1, part2, rowstat, w, lane, tid);
    }

    // ---- decoder layer 3: 512 -> 64 (MFMA) + bias, store fp32 ----
    {
        const int mt = w >> 2, nt = w & 3;
        f32x4 acc = (f32x4){0.f, 0.f, 0.f, 0.f};
#pragma unroll 4
        for (int kc = 0; kc < H / 32; ++kc) {
            const int k0 = kc * 32 + q * 8;
            short8 a = *(const short8*)&actA[mt * 16 + lm][k0];
            short8 b = *(const short8*)&dW3T[(nt * 16 + lm) * H + k0];
            acc = __builtin_amdgcn_mfma_f32_16x16x32_bf16(a, b, acc, 0, 0, 0);
        }
        const int c = nt * 16 + lm;
        const float bb = db3[c];
#pragma unroll
        for (int r = 0; r < 4; ++r) {
            const int row = mt * 16 + q * 4 + r;
            out[(row0 + row) * NX + c] = acc[r] + bb;
        }
    }
}

// =================== fallback (round-1 fp32 kernel) if ws too small ===================
#define FB_R 16
#define FB_STRIDE 520
#define FB_NT 256

__device__ __forceinline__ void fb_ln_silu(float buf[FB_R][FB_STRIDE],
                                           const float* __restrict__ g,
                                           const float* __restrict__ be, int t) {
    const int r = t >> 4, lane = t & 15;
    float s1 = 0.f, s2 = 0.f;
#pragma unroll
    for (int j = 0; j < H / 16; ++j) {
        float v = buf[r][lane + 16 * j];
        s1 += v; s2 += v * v;
    }
#pragma unroll
    for (int m = 8; m >= 1; m >>= 1) {
        s1 += __shfl_xor(s1, m, 16);
        s2 += __shfl_xor(s2, m, 16);
    }
    const float mean = s1 * (1.0f / H);
    const float var = s2 * (1.0f / H) - mean * mean;
    const float rstd = rsqrtf(var + 1e-5f);
#pragma unroll
    for (int j = 0; j < H / 16; ++j) {
        const int c = lane + 16 * j;
        float v = buf[r][c];
        buf[r][c] = silu_f((v - mean) * rstd * g[c] + be[c]);
    }
}

template <int K>
__device__ __forceinline__ void fb_gemmK(const float in[FB_R][FB_STRIDE], float out[FB_R][FB_STRIDE],
                                         const float* __restrict__ W,
                                         const float* __restrict__ b, int t) {
    const int c0 = t, c1 = t + 256;
    float acc0[FB_R], acc1[FB_R];
#pragma unroll
    for (int r = 0; r < FB_R; ++r) { acc0[r] = 0.f; acc1[r] = 0.f; }
    for (int k = 0; k < K; k += 4) {
        const float w00 = W[(k + 0) * H + c0], w10 = W[(k + 0) * H + c1];
        const float w01 = W[(k + 1) * H + c0], w11 = W[(k + 1) * H + c1];
        const float w02 = W[(k + 2) * H + c0], w12 = W[(k + 2) * H + c1];
        const float w03 = W[(k + 3) * H + c0], w13 = W[(k + 3) * H + c1];
#pragma unroll
        for (int r = 0; r < FB_R; ++r) {
            const float4 h = *(const float4*)&in[r][k];
            acc0[r] += h.x * w00 + h.y * w01 + h.z * w02 + h.w * w03;
            acc1[r] += h.x * w10 + h.y * w11 + h.z * w12 + h.w * w13;
        }
    }
    const float b0 = b[c0], b1 = b[c1];
#pragma unroll
    for (int r = 0; r < FB_R; ++r) {
        out[r][c0] = acc0[r] + b0;
        out[r][c1] = acc1[r] + b1;
    }
}

__global__ __launch_bounds__(FB_NT, 2) void sindy_fallback_kernel(
    const float* __restrict__ x0, const float* __restrict__ logdt,
    const float* __restrict__ eW1, const float* __restrict__ eb1,
    const float* __restrict__ eg1, const float* __restrict__ ebe1,
    const float* __restrict__ eW2, const float* __restrict__ eb2,
    const float* __restrict__ eg2, const float* __restrict__ ebe2,
    const float* __restrict__ eW3, const float* __restrict__ eb3,
    const float* __restrict__ dW1, const float* __restrict__ db1,
    const float* __restrict__ dg1, const float* __restrict__ dbe1,
    const float* __restrict__ dW2, const float* __restrict__ db2,
    const float* __restrict__ dg2, const float* __restrict__ dbe2,
    const float* __restrict__ dW3, const float* __restrict__ db3,
    const float* __restrict__ Xi, float* __restrict__ out) {
    __shared__ float sA[FB_R][FB_STRIDE];
    __shared__ float sB[FB_R][FB_STRIDE];
    __shared__ float zbuf[FB_R][LD];
    __shared__ float dtb[FB_R];
    __shared__ float xis[NT * LD];

    const int t = threadIdx.x;
    const int row0 = blockIdx.x * FB_R;

    for (int i = t; i < NT * LD; i += FB_NT) xis[i] = Xi[i];
    if (t < FB_R) dtb[t] = logdt[row0 + t] * (1.0f / NSTEPS);
    {
        const int r = t >> 4, k4 = (t & 15) * 4;
        *(float4*)&sB[r][k4] = *(const float4*)&x0[(row0 + r) * NX + k4];
    }
    __syncthreads();
    fb_gemmK<NX>(sB, sA, eW1, eb1, t);
    __syncthreads();
    fb_ln_silu(sA, eg1, ebe1, t);
    __syncthreads();
    fb_gemmK<H>(sA, sB, eW2, eb2, t);
    __syncthreads();
    fb_ln_silu(sB, eg2, ebe2, t);
    __syncthreads();
    if (t < FB_R * LD) {
        const int r = t >> 3, c = t & 7;
        float acc = 0.f;
        for (int k = 0; k < H; k += 4) {
            const float4 h = *(const float4*)&sB[r][k];
            acc += h.x * eW3[(k + 0) * LD + c] + h.y * eW3[(k + 1) * LD + c] +
                   h.z * eW3[(k + 2) * LD + c] + h.w * eW3[(k + 3) * LD + c];
        }
        zbuf[r][c] = tanhf(acc + eb3[c]);
    }
    __syncthreads();
    for (int s = 0; s < NSTEPS; ++s) {
        float zn = 0.f;
        const int r = t >> 3, c = t & 7;
        if (t < FB_R * LD) {
            float z[LD];
#pragma unroll
            for (int j = 0; j < LD; ++j) z[j] = zbuf[r][j];
            float zd = xis[c];
#pragma unroll
            for (int j = 0; j < LD; ++j) zd += z[j] * xis[(1 + j) * LD + c];
            int idx = 1 + LD;
#pragma unroll
            for (int i = 0; i < LD; ++i)
#pragma unroll
                for (int j = i; j < LD; ++j) {
                    zd += z[i] * z[j] * xis[idx * LD + c];
                    ++idx;
                }
            zn = z[c] + zd * dtb[r];
        }
        __syncthreads();
        if (t < FB_R * LD) zbuf[r][c] = zn;
        __syncthreads();
    }
    {
        const int c0 = t, c1 = t + 256;
        float acc0[FB_R], acc1[FB_R];
#pragma unroll
        for (int r = 0; r < FB_R; ++r) { acc0[r] = 0.f; acc1[r] = 0.f; }
#pragma unroll
        for (int k = 0; k < LD; ++k) {
            const float w0 = dW1[k * H + c0], w1 = dW1[k * H + c1];
#pragma unroll
            for (int r = 0; r < FB_R; ++r) {
                const float zv = zbuf[r][k];
                acc0[r] += zv * w0;
                acc1[r] += zv * w1;
            }
        }
        const float b0 = db1[c0], b1v = db1[c1];
#pragma unroll
        for (int r = 0; r < FB_R; ++r) {
            sA[r][c0] = acc0[r] + b0;
            sA[r][c1] = acc1[r] + b1v;
        }
    }
    __syncthreads();
    fb_ln_silu(sA, dg1, dbe1, t);
    __syncthreads();
    fb_gemmK<H>(sA, sB, dW2, db2, t);
    __syncthreads();
    fb_ln_silu(sB, dg2, dbe2, t);
    __syncthreads();
    {
        const int c = t & 63;
        const int rb = t >> 6;
        float acc[4] = {0.f, 0.f, 0.f, 0.f};
        for (int k = 0; k < H; k += 4) {
            const float w0 = dW3[(k + 0) * NX + c];
            const float w1 = dW3[(k + 1) * NX + c];
            const float w2 = dW3[(k + 2) * NX + c];
            const float w3 = dW3[(k + 3) * NX + c];
#pragma unroll
            for (int i = 0; i < 4; ++i) {
                const int r = rb + 4 * i;
                const float4 h = *(const float4*)&sB[r][k];
                acc[i] += h.x * w0 + h.y * w1 + h.z * w2 + h.w * w3;
            }
        }
        const float bb = db3[c];
#pragma unroll
        for (int i = 0; i < 4; ++i) {
            const int r = rb + 4 * i;
            out[(row0 + r) * NX + c] = acc[i] + bb;
        }
    }
}

extern "C" void kernel_launch(void* const* d_in, const int* in_sizes, int n_in,
                              void* d_out, int out_size, void* d_ws, size_t ws_size,
                              hipStream_t stream) {
    const float* x0    = (const float*)d_in[0];
    const float* logdt = (const float*)d_in[1];
    const float* eW1  = (const float*)d_in[4];
    const float* eb1  = (const float*)d_in[5];
    const float* eg1  = (const float*)d_in[6];
    const float* ebe1 = (const float*)d_in[7];
    const float* eW2  = (const float*)d_in[8];
    const float* eb2  = (const float*)d_in[9];
    const float* eg2  = (const float*)d_in[10];
    const float* ebe2 = (const float*)d_in[11];
    const float* eW3  = (const float*)d_in[12];
    const float* eb3  = (const float*)d_in[13];
    const float* dW1  = (const float*)d_in[14];
    const float* db1  = (const float*)d_in[15];
    const float* dg1  = (const float*)d_in[16];
    const float* dbe1 = (const float*)d_in[17];
    const float* dW2  = (const float*)d_in[18];
    const float* db2  = (const float*)d_in[19];
    const float* dg2  = (const float*)d_in[20];
    const float* dbe2 = (const float*)d_in[21];
    const float* dW3  = (const float*)d_in[22];
    const float* db3  = (const float*)d_in[23];
    const float* Xi   = (const float*)d_in[24];
    float* out = (float*)d_out;

    if (ws_size >= (size_t)WS_ELEMS * sizeof(short)) {
        short* wsb = (short*)d_ws;
        prep_weights<<<WS_ELEMS / 256, 256, 0, stream>>>(eW1, eW2, dW2, dW3, wsb);
        sindy_mfma_kernel<<<B_TOTAL / ROWS, NTH, 0, stream>>>(
            x0, logdt, eb1, eg1, ebe1, eb2, eg2, ebe2, eW3, eb3,
            dW1, db1, dg1, dbe1, db2, dg2, dbe2, db3, Xi, wsb, out);
    } else {
        sindy_fallback_kernel<<<B_TOTAL / FB_R, FB_NT, 0, stream>>>(
            x0, logdt, eW1, eb1, eg1, ebe1, eW2, eb2, eg2, ebe2, eW3, eb3,
            dW1, db1, dg1, dbe1, dW2, db2, dg2, dbe2, dW3, db3, Xi, out);
    }
}